// Round 1
// baseline (383.881 us; speedup 1.0000x reference)
//
#include <hip/hip_runtime.h>

#define LSTM_H 20
#define LSTM_4H 80

// sigmoid(x) = 1 / (1 + 2^(-x*log2(e)))
__device__ __forceinline__ float fsig(float x) {
    float e = __builtin_amdgcn_exp2f(x * -1.44269504088896340736f);
    return __builtin_amdgcn_rcpf(1.0f + e);
}
// tanh(x) = 2*sigmoid(2x) - 1 = 2 / (1 + 2^(-2x*log2(e))) - 1
__device__ __forceinline__ float ftanh(float x) {
    float e = __builtin_amdgcn_exp2f(x * -2.88539008177792681471f);
    return __builtin_amdgcn_rcpf(1.0f + e) * 2.0f - 1.0f;
}

__global__ __launch_bounds__(256) void coordwise_lstm_kernel(
    const float* __restrict__ params, const float* __restrict__ grads,
    const float* __restrict__ h0, const float* __restrict__ c0,
    const float* __restrict__ W_ih, const float* __restrict__ W_hh,
    const float* __restrict__ b_ih, const float* __restrict__ b_hh,
    const float* __restrict__ W_out, const float* __restrict__ b_out,
    float* __restrict__ out, int n)
{
    // Stage all weights in LDS (~7.4 KB). All lanes read the same address at
    // the same time -> broadcast, conflict-free.
    __shared__ float sWhh[LSTM_4H * LSTM_H];   // [80][20]
    __shared__ float sWih[LSTM_4H * 2];        // [80][2]
    __shared__ float sB[LSTM_4H];              // b_ih + b_hh
    __shared__ float sWout[LSTM_H];
    __shared__ float sBout;

    for (int t = threadIdx.x; t < LSTM_4H * LSTM_H; t += 256) sWhh[t] = W_hh[t];
    for (int t = threadIdx.x; t < LSTM_4H * 2;      t += 256) sWih[t] = W_ih[t];
    for (int t = threadIdx.x; t < LSTM_4H;          t += 256) sB[t]   = b_ih[t] + b_hh[t];
    if (threadIdx.x < LSTM_H) sWout[threadIdx.x] = W_out[threadIdx.x];
    if (threadIdx.x == 0) sBout = b_out[0];
    __syncthreads();

    const int i = blockIdx.x * 256 + threadIdx.x;
    if (i >= n) return;

    const float g = grads[i];
    const float p = params[i];

    // h0/c0 rows: 20 floats = 80 B, 16B-aligned (80 = 5*16) -> 5x float4 each.
    float hv[LSTM_H], cv[LSTM_H];
    const float4* h4 = reinterpret_cast<const float4*>(h0) + (size_t)i * (LSTM_H / 4);
    const float4* c4 = reinterpret_cast<const float4*>(c0) + (size_t)i * (LSTM_H / 4);
    #pragma unroll
    for (int q = 0; q < LSTM_H / 4; ++q) {
        float4 a = h4[q];
        hv[4*q+0] = a.x; hv[4*q+1] = a.y; hv[4*q+2] = a.z; hv[4*q+3] = a.w;
        float4 b = c4[q];
        cv[4*q+0] = b.x; cv[4*q+1] = b.y; cv[4*q+2] = b.z; cv[4*q+3] = b.w;
    }

    float upd = sBout;
    #pragma unroll 2
    for (int k = 0; k < LSTM_H; ++k) {
        // PyTorch gate order: rows [0,20)=i, [20,40)=f, [40,60)=g, [60,80)=o
        float gi = sB[k]            + sWih[2*k]              * g + sWih[2*k+1]              * p;
        float gf = sB[k+LSTM_H]     + sWih[2*(k+LSTM_H)]     * g + sWih[2*(k+LSTM_H)+1]     * p;
        float gg = sB[k+2*LSTM_H]   + sWih[2*(k+2*LSTM_H)]   * g + sWih[2*(k+2*LSTM_H)+1]   * p;
        float go = sB[k+3*LSTM_H]   + sWih[2*(k+3*LSTM_H)]   * g + sWih[2*(k+3*LSTM_H)+1]   * p;
        const float* wi = &sWhh[(k)            * LSTM_H];
        const float* wf = &sWhh[(k+LSTM_H)     * LSTM_H];
        const float* wg = &sWhh[(k+2*LSTM_H)   * LSTM_H];
        const float* wo = &sWhh[(k+3*LSTM_H)   * LSTM_H];
        #pragma unroll
        for (int kk = 0; kk < LSTM_H; ++kk) {
            const float h = hv[kk];
            gi = fmaf(wi[kk], h, gi);
            gf = fmaf(wf[kk], h, gf);
            gg = fmaf(wg[kk], h, gg);
            go = fmaf(wo[kk], h, go);
        }
        const float c1 = fsig(gf) * cv[k] + fsig(gi) * ftanh(gg);
        const float h1 = fsig(go) * ftanh(c1);
        upd = fmaf(sWout[k], h1, upd);
    }
    out[i] = upd;
}

extern "C" void kernel_launch(void* const* d_in, const int* in_sizes, int n_in,
                              void* d_out, int out_size, void* d_ws, size_t ws_size,
                              hipStream_t stream) {
    const float* params = (const float*)d_in[0];
    const float* grads  = (const float*)d_in[1];
    const float* h0     = (const float*)d_in[2];
    const float* c0     = (const float*)d_in[3];
    const float* W_ih   = (const float*)d_in[4];
    const float* W_hh   = (const float*)d_in[5];
    const float* b_ih   = (const float*)d_in[6];
    const float* b_hh   = (const float*)d_in[7];
    const float* W_out  = (const float*)d_in[8];
    const float* b_out  = (const float*)d_in[9];
    float* out = (float*)d_out;

    const int n = in_sizes[0];
    const int blocks = (n + 255) / 256;
    hipLaunchKernelGGL(coordwise_lstm_kernel, dim3(blocks), dim3(256), 0, stream,
                       params, grads, h0, c0, W_ih, W_hh, b_ih, b_hh, W_out, b_out,
                       out, n);
}